// Round 17
// baseline (36.039 us; speedup 1.0000x reference)
//
#include <hip/hip_runtime.h>

// Problem constants (from reference setup_inputs)
#define BB 8
#define QQ 30
#define DD 1500
#define EE 768
#define KK 11
#define WW 736      // (1500-30)/2 + 1
#define WIN 30
#define STR 2

#define NT 94       // n-tiles of 16 d (94*16 = 1504 >= 1500)
#define KS 2        // K-split across grid (2 x 384)
#define DCH 544     // windows chunk d-extent (2*255+29+1 = 540, padded)

typedef __attribute__((ext_vector_type(8))) __bf16 bf16x8;
typedef __attribute__((ext_vector_type(4))) float f32x4;
typedef __attribute__((ext_vector_type(4))) unsigned int uint4v;

// ---------------------------------------------------------------------------
// truncation split: x = hi + lo + O(2^-16 x); ~48 VALU per 8 elems.
// Dropped a*b terms ~3*2^-16 |ab| -> cos abs err ~2e-6 (R16-validated).
// ---------------------------------------------------------------------------
__device__ inline void split8(const float4 va, const float4 vb,
                              bf16x8& bh, bf16x8& bl, float& ssq)
{
    float f[8] = {va.x, va.y, va.z, va.w, vb.x, vb.y, vb.z, vb.w};
    unsigned hu[8];
    float r[8];
    #pragma unroll
    for (int j = 0; j < 8; j++) {
        float x = f[j];
        ssq += x * x;
        unsigned hb = __float_as_uint(x) & 0xffff0000u;
        hu[j] = hb;
        r[j] = x - __uint_as_float(hb);
    }
    uint4v uh, ul;
    #pragma unroll
    for (int j = 0; j < 4; j++) {
        uh[j] = hu[2 * j + 1] | (hu[2 * j] >> 16);
        unsigned l0 = __float_as_uint(r[2 * j]) >> 16;
        unsigned l1 = __float_as_uint(r[2 * j + 1]) & 0xffff0000u;
        ul[j] = l1 | l0;
    }
    bh = __builtin_bit_cast(bf16x8, uh);
    bl = __builtin_bit_cast(bf16x8, ul);
}

#define MFMA(a, b, c) __builtin_amdgcn_mfma_f32_16x16x32_bf16(a, b, c, 0, 0, 0)

// ---------------------------------------------------------------------------
// Kernel 1 (v8): split-bf16 MFMA GEMM, K-split 2 across grid for occupancy.
// Block: 16 d x 30 q x K=384 (wave = 96); writes RAW partial dot + partial
// d/q ssq (normalization deferred to windows phase 1). qssq partials are
// written redundantly by all nt-blocks -- bit-identical, deterministic.
// grid = (94 n-tiles, 2 k-halves, 8 batches) = 1504 blocks ~ 5.9/CU.
// ---------------------------------------------------------------------------
__global__ __launch_bounds__(256) void skl_gemm(
    const float* __restrict__ qe,      // [8][30][768]
    const float* __restrict__ de,      // [8][1500][768]
    float* __restrict__ cpart,         // [2][240][1500] raw dot partials
    float* __restrict__ dssqp,         // [2][8][1500]
    float* __restrict__ qssqp)         // [2][240]
{
    __shared__ float red[4][64][12];   // acc0(4) acc1(4) dssq qssq0 qssq1 pad
    int tid = threadIdx.x;
    int wave = tid >> 6, lane = tid & 63;
    int ln = lane & 15, g = lane >> 4;
    int nt = blockIdx.x, ks = blockIdx.y, b = blockIdx.z;
    int d = nt * 16 + ln;
    int dc = min(d, DD - 1);
    const float* drow  = de + ((size_t)b * DD + dc) * EE;
    int r1 = min(16 + ln, QQ - 1);     // clamp: rows 30,31 unused in output
    const float* qrow0 = qe + ((size_t)b * QQ + ln) * EE;
    const float* qrow1 = qe + ((size_t)b * QQ + r1) * EE;

    f32x4 acc0 = {0.f, 0.f, 0.f, 0.f};
    f32x4 acc1 = {0.f, 0.f, 0.f, 0.f};
    float dssq = 0.f, qssq0 = 0.f, qssq1 = 0.f;
    int k0 = ks * 384 + wave * 96;

    #pragma unroll
    for (int kst = 0; kst < 3; kst++) {
        int e0 = k0 + kst * 32 + 8 * g;
        bf16x8 a0h, a0l, a1h, a1l, bh, bl;
        {
            float4 va = *(const float4*)&qrow0[e0];
            float4 vb = *(const float4*)&qrow0[e0 + 4];
            split8(va, vb, a0h, a0l, qssq0);
        }
        {
            float4 va = *(const float4*)&qrow1[e0];
            float4 vb = *(const float4*)&qrow1[e0 + 4];
            split8(va, vb, a1h, a1l, qssq1);
        }
        {
            float4 va = *(const float4*)&drow[e0];
            float4 vb = *(const float4*)&drow[e0 + 4];
            split8(va, vb, bh, bl, dssq);
        }
        acc0 = MFMA(a0h, bh, acc0);
        acc0 = MFMA(a0h, bl, acc0);
        acc0 = MFMA(a0l, bh, acc0);
        acc1 = MFMA(a1h, bh, acc1);
        acc1 = MFMA(a1h, bl, acc1);
        acc1 = MFMA(a1l, bh, acc1);
    }

    // reduce ssq over the 4 k-groups (lane bits 4,5)
    dssq  += __shfl_xor(dssq, 16);  dssq  += __shfl_xor(dssq, 32);
    qssq0 += __shfl_xor(qssq0, 16); qssq0 += __shfl_xor(qssq0, 32);
    qssq1 += __shfl_xor(qssq1, 16); qssq1 += __shfl_xor(qssq1, 32);

    #pragma unroll
    for (int j = 0; j < 4; j++) {
        red[wave][lane][j] = acc0[j];
        red[wave][lane][4 + j] = acc1[j];
    }
    red[wave][lane][8] = dssq;
    red[wave][lane][9] = qssq0;
    red[wave][lane][10] = qssq1;
    __syncthreads();

    if (tid < 16) {     // q-row ssq partials (rows tid and 16+tid)
        float q0 = 0.f, q1 = 0.f;
        #pragma unroll
        for (int w = 0; w < 4; w++) {
            q0 += red[w][tid][9];
            q1 += red[w][tid][10];
        }
        // identical value from every nt-block: benign duplicate write
        qssqp[ks * (BB * QQ) + b * QQ + tid] = q0;
        if (16 + tid < QQ) qssqp[ks * (BB * QQ) + b * QQ + 16 + tid] = q1;
    }

    if (wave == 0) {
        float a0f[4] = {0.f, 0.f, 0.f, 0.f};
        float a1f[4] = {0.f, 0.f, 0.f, 0.f};
        float sf = 0.f;
        #pragma unroll
        for (int w = 0; w < 4; w++) {
            #pragma unroll
            for (int j = 0; j < 4; j++) {
                a0f[j] += red[w][lane][j];
                a1f[j] += red[w][lane][4 + j];
            }
            sf += red[w][lane][8];
        }
        if (d < DD) {
            size_t sbase = (size_t)ks * (BB * QQ) * DD;
            #pragma unroll
            for (int j = 0; j < 4; j++) {
                int q0 = 4 * g + j;     // C row = 4g+j, col = ln
                cpart[sbase + ((size_t)b * QQ + q0) * DD + d] = a0f[j];
                int q1i = 16 + q0;
                if (q1i < QQ)
                    cpart[sbase + ((size_t)b * QQ + q1i) * DD + d] = a1f[j];
            }
            dssqp[((size_t)ks * BB + b) * DD + d] = sf;
        }
    }
}

// ---------------------------------------------------------------------------
// Kernel 2: assemble cosine from partials (2 dot + 2 dssq + qinv) ->
// RBF (f32 __expf) -> window sums -> saturation -> pscore.
// Block per (b,q,chunk of 256 windows) = 720 blocks. No sync primitives.
// ---------------------------------------------------------------------------
__global__ __launch_bounds__(256) void skl_windows(
    const float* __restrict__ cpart,   // [2][240][1500]
    const float* __restrict__ dssqp,   // [2][8][1500]
    const float* __restrict__ qssqp,   // [2][240]
    const float* __restrict__ dmask,   // [8][1500]
    const float* __restrict__ qmask,   // [8][30]
    const float* __restrict__ qidfs,   // [240]
    const float* __restrict__ mu,      // [11]
    const float* __restrict__ sigma,   // [11]
    const float* __restrict__ w1, const float* __restrict__ b1,
    const float* __restrict__ w2, const float* __restrict__ b2,
    const float* __restrict__ w3, const float* __restrict__ b3,
    const float* __restrict__ dw,      // [11]
    float* __restrict__ pscore)        // [240][736]
{
    __shared__ float vf[KK][DCH];      // 23.9 KB
    __shared__ float fl[DCH];          // 2.2 KB

    int bid = blockIdx.x;     // 0..719
    int c  = bid % 3;
    int bq = bid / 3;         // 0..239
    int b  = bq / QQ;
    int tid = threadIdx.x;

    int dbase = 512 * c;
    int dcount = min(540, DD - dbase);
    int w = c * 256 + tid;
    bool active = (w < WW);

    float muL[KK], i2s[KK], dwL[KK];
    #pragma unroll
    for (int k = 0; k < KK; k++) {
        muL[k] = mu[k];
        float s = sigma[k];
        i2s[k] = 1.f / (2.f * s * s);
        dwL[k] = dw[k];
    }
    const float* dm = dmask + (size_t)b * DD + dbase;
    const float* c0 = cpart + (size_t)bq * DD + dbase;
    const float* c1 = c0 + (size_t)(BB * QQ) * DD;
    const float* s0p = dssqp + (size_t)b * DD + dbase;
    const float* s1p = s0p + (size_t)BB * DD;
    float qin = 1.f / fmaxf(sqrtf(qssqp[bq] + qssqp[BB * QQ + bq]), 1e-13f);

    // phase 1: assemble cosine, then 11 RBF values per d
    for (int i = tid; i < dcount; i += 256) {
        float dot = c0[i] + c1[i];
        float dsq = s0p[i] + s1p[i];
        float invd = 1.f / fmaxf(sqrtf(dsq), 1e-13f);
        float cc = dot * invd * qin;
        float m = dm[i];
        float ssum = 0.f;
        #pragma unroll
        for (int k = 0; k < KK; k++) {
            float diff = cc - muL[k];
            float val = __expf(-diff * diff * i2s[k]) * m;
            ssum += val;
            vf[k][i] = val;
        }
        fl[i] = (ssum != 0.f) ? 1.f : 0.f;
    }
    __syncthreads();

    // phase 2: per-window sums + saturation + dense_w
    if (active) {
        int dl = 2 * tid;
        float pk[KK];
        #pragma unroll
        for (int k = 0; k < KK; k++) pk[k] = 0.f;
        float lenf = 0.f;
        #pragma unroll
        for (int j2 = 0; j2 < WIN / 2; j2++) {
            float2 f2 = *(const float2*)&fl[dl + 2 * j2];
            lenf += f2.x + f2.y;
            #pragma unroll
            for (int k = 0; k < KK; k++) {
                float2 v2 = *(const float2*)&vf[k][dl + 2 * j2];
                pk[k] += v2.x + v2.y;
            }
        }
        float idf = fmaxf(qidfs[bq], 0.f);
        float sat1 = idf * w1[0] + lenf * w1[1] + b1[0];
        float sat2 = 1.f / (idf * w2[0] + lenf * w2[1] + b2[0]);
        float sat3 = idf * w3[0] + lenf * w3[1] + b3[0];
        float mult = qmask[bq] * (lenf > 0.f ? 1.f : 0.f);

        float acc = 0.f;
        #pragma unroll
        for (int k = 0; k < KK; k++) {
            float x = fmaxf(pk[k], 1e-10f);
            float p = exp2f(sat2 * __log2f(x));
            acc += (sat1 * p - sat3) * dwL[k];
        }
        pscore[(size_t)bq * WW + w] = acc * mult;
    }
}

// ---------------------------------------------------------------------------
// Kernel 3: per batch: sum over q (float4-vectorized), then single-wave
// top-3 argmax + pooling + gather.
// ---------------------------------------------------------------------------
__global__ __launch_bounds__(256) void skl_topk(
    const float* __restrict__ pscore,  // [240][736]
    const float* __restrict__ chunk,   // [15]
    float* __restrict__ out)           // [8]
{
    __shared__ float s0[WW];
    int b = blockIdx.x;
    int tid = threadIdx.x;

    if (tid < WW / 4) {                // 184 threads, one float4 of w each
        float4 s = make_float4(0.f, 0.f, 0.f, 0.f);
        for (int q = 0; q < QQ; q++) {
            float4 v = *(const float4*)&pscore[(size_t)(b * QQ + q) * WW + 4 * tid];
            s.x += v.x; s.y += v.y; s.z += v.z; s.w += v.w;
        }
        s0[4 * tid + 0] = (s.x == 0.f) ? -9900.f : s.x;
        s0[4 * tid + 1] = (s.y == 0.f) ? -9900.f : s.y;
        s0[4 * tid + 2] = (s.z == 0.f) ? -9900.f : s.z;
        s0[4 * tid + 3] = (s.w == 0.f) ? -9900.f : s.w;
    }
    __syncthreads();

    if (tid < 64) {
        int lane = tid;
        float m[12];
        #pragma unroll
        for (int r = 0; r < 12; r++) {
            int w = lane + 64 * r;
            m[r] = (w < WW) ? s0[w] : -3.3e38f;
        }

        int best[3];
        for (int c = 0; c < 3; c++) {
            float bv = -3.3e38f;
            int bi = 1 << 30;
            #pragma unroll
            for (int r = 0; r < 12; r++) {
                int w = lane + 64 * r;
                if (w < WW && m[r] > bv) { bv = m[r]; bi = w; }
            }
            #pragma unroll
            for (int off = 32; off >= 1; off >>= 1) {
                float ov = __shfl_down(bv, off);
                int oi = __shfl_down(bi, off);
                if (ov > bv || (ov == bv && oi < bi)) { bv = ov; bi = oi; }
            }
            bi = __shfl(bi, 0);
            best[c] = bi;
            float pen = -10001.f - (float)c;
            #pragma unroll
            for (int r = 0; r < 12; r++) {
                int w = lane + 64 * r;
                int dd = w - bi; if (dd < 0) dd = -dd;
                if (w < WW && dd < 15) m[r] = pen;
            }
        }

        float contrib = 0.f;
        if (lane < 15) {
            int c = lane % 3;
            int g = lane / 3;
            const int offs[5] = {0, -1, 1, -2, 2};
            int nb = best[c] + offs[g];
            nb = min(max(nb, 0), WW - 1);
            float v = s0[nb];
            if (v <= -9900.f) v = 0.f;
            contrib = v * chunk[lane];
        }
        #pragma unroll
        for (int off = 32; off >= 1; off >>= 1) contrib += __shfl_down(contrib, off);
        if (lane == 0) out[b] = contrib;
    }
}

// ---------------------------------------------------------------------------
extern "C" void kernel_launch(void* const* d_in, const int* in_sizes, int n_in,
                              void* d_out, int out_size, void* d_ws, size_t ws_size,
                              hipStream_t stream) {
    const float* qe    = (const float*)d_in[0];   // (8,30,768)
    const float* de    = (const float*)d_in[1];   // (8,1500,768)
    const float* qmask = (const float*)d_in[2];   // (8,30)
    const float* dmask = (const float*)d_in[3];   // (8,1500)
    const float* qidfs = (const float*)d_in[4];   // (8,30,1)
    // d_in[5] = document_idfs (unused)
    const float* mu    = (const float*)d_in[6];   // (11,)
    const float* sigma = (const float*)d_in[7];   // (11,)
    const float* w1    = (const float*)d_in[8];
    const float* b1    = (const float*)d_in[9];
    const float* w2    = (const float*)d_in[10];
    const float* b2    = (const float*)d_in[11];
    const float* w3    = (const float*)d_in[12];
    const float* b3    = (const float*)d_in[13];
    const float* dw    = (const float*)d_in[14];  // (1,11)
    const float* chunk = (const float*)d_in[15];  // (1,15)
    float* out = (float*)d_out;

    float* ws = (float*)d_ws;
    float* cpart  = ws;                      // 2*240*1500 = 720,000 f32
    float* dssqp  = ws + 720000;             // 2*8*1500   =  24,000 f32
    float* qssqp  = ws + 744000;             // 2*240      =     480 f32
    float* pscore = ws + 744512;             // 240*736    = 176,640 f32 (~3.7MB)

    skl_gemm<<<dim3(NT, KS, BB), 256, 0, stream>>>(qe, de, cpart, dssqp, qssqp);
    skl_windows<<<BB * QQ * 3, 256, 0, stream>>>(cpart, dssqp, qssqp, dmask,
                                                 qmask, qidfs, mu, sigma,
                                                 w1, b1, w2, b2, w3, b3,
                                                 dw, pscore);
    skl_topk<<<BB, 256, 0, stream>>>(pscore, chunk, out);
}

// Round 18
// 33.846 us; speedup vs baseline: 1.0648x; 1.0648x over previous
//
#include <hip/hip_runtime.h>

// Problem constants (from reference setup_inputs)
#define BB 8
#define QQ 30
#define DD 1500
#define EE 768
#define KK 11
#define WW 736      // (1500-30)/2 + 1
#define WIN 30
#define STR 2

#define NT 94       // n-tiles of 16 d (94*16 = 1504 >= 1500)
#define DCH 544     // windows chunk d-extent (2*255+29+1 = 540, padded)

typedef __attribute__((ext_vector_type(8))) __bf16 bf16x8;
typedef __attribute__((ext_vector_type(4))) float f32x4;
typedef __attribute__((ext_vector_type(4))) unsigned int uint4v;

// ---------------------------------------------------------------------------
// truncation split: x = hi + lo + O(2^-16 x); hi = bf16-trunc(x) (bit mask,
// no shift needed for the f32 value), lo = bf16-trunc(x - hi).
// Dropped terms in a*b: lo_a*lo_b + trunc residuals ~ 3*2^-16 |ab| -- cos
// abs error ~2e-6, ~250x below the argmax-flip scale established in R1.
// ~48 VALU per 8 elems (vs ~120 for the RNE version).
// ---------------------------------------------------------------------------
__device__ inline void split8(const float4 va, const float4 vb,
                              bf16x8& bh, bf16x8& bl, float& ssq)
{
    float f[8] = {va.x, va.y, va.z, va.w, vb.x, vb.y, vb.z, vb.w};
    unsigned hu[8];
    float r[8];
    #pragma unroll
    for (int j = 0; j < 8; j++) {
        float x = f[j];
        ssq += x * x;
        unsigned hb = __float_as_uint(x) & 0xffff0000u;
        hu[j] = hb;
        r[j] = x - __uint_as_float(hb);
    }
    uint4v uh, ul;
    #pragma unroll
    for (int j = 0; j < 4; j++) {
        uh[j] = hu[2 * j + 1] | (hu[2 * j] >> 16);
        unsigned l0 = __float_as_uint(r[2 * j]) >> 16;
        unsigned l1 = __float_as_uint(r[2 * j + 1]) & 0xffff0000u;
        ul[j] = l1 | l0;
    }
    bh = __builtin_bit_cast(bf16x8, uh);
    bl = __builtin_bit_cast(bf16x8, ul);
}

#define MFMA(a, b, c) __builtin_amdgcn_mfma_f32_16x16x32_bf16(a, b, c, 0, 0, 0)

// ---------------------------------------------------------------------------
// Kernel 1: split-bf16 MFMA GEMM with INLINE normalization (both q and d).
// Block: 16 d x 30 q x K=768; wave w covers K-range [192w, 192w+192).
// Loads raw f32 qe/de, truncation-splits to bf16 hi/lo in-registers,
// accumulates q-row and d-row ssq alongside; LDS reduce over 4 waves;
// writes final cosine = dot / (|q||d|).  grid = (94 n-tiles, 8 batches).
// ---------------------------------------------------------------------------
__global__ __launch_bounds__(256) void skl_gemm(
    const float* __restrict__ qe,      // [8][30][768]
    const float* __restrict__ de,      // [8][1500][768]
    float* __restrict__ cosm)          // [8][30][1500] final cosine
{
    __shared__ float red[4][64][12];   // acc0(4) acc1(4) dssq qssq0 qssq1 pad
    __shared__ float qinv[32];
    int tid = threadIdx.x;
    int wave = tid >> 6, lane = tid & 63;
    int ln = lane & 15, g = lane >> 4;
    int nt = blockIdx.x, b = blockIdx.y;
    int d = nt * 16 + ln;
    int dc = min(d, DD - 1);
    const float* drow  = de + ((size_t)b * DD + dc) * EE;
    int r1 = min(16 + ln, QQ - 1);     // clamp: rows 30,31 unused in output
    const float* qrow0 = qe + ((size_t)b * QQ + ln) * EE;
    const float* qrow1 = qe + ((size_t)b * QQ + r1) * EE;

    f32x4 acc0 = {0.f, 0.f, 0.f, 0.f};
    f32x4 acc1 = {0.f, 0.f, 0.f, 0.f};
    float dssq = 0.f, qssq0 = 0.f, qssq1 = 0.f;
    int k0 = wave * 192;

    #pragma unroll
    for (int kst = 0; kst < 6; kst++) {
        int e0 = k0 + kst * 32 + 8 * g;
        bf16x8 a0h, a0l, a1h, a1l, bh, bl;
        {
            float4 va = *(const float4*)&qrow0[e0];
            float4 vb = *(const float4*)&qrow0[e0 + 4];
            split8(va, vb, a0h, a0l, qssq0);
        }
        {
            float4 va = *(const float4*)&qrow1[e0];
            float4 vb = *(const float4*)&qrow1[e0 + 4];
            split8(va, vb, a1h, a1l, qssq1);
        }
        {
            float4 va = *(const float4*)&drow[e0];
            float4 vb = *(const float4*)&drow[e0 + 4];
            split8(va, vb, bh, bl, dssq);
        }
        acc0 = MFMA(a0h, bh, acc0);
        acc0 = MFMA(a0h, bl, acc0);
        acc0 = MFMA(a0l, bh, acc0);
        acc1 = MFMA(a1h, bh, acc1);
        acc1 = MFMA(a1h, bl, acc1);
        acc1 = MFMA(a1l, bh, acc1);
    }

    // reduce ssq over the 4 k-groups (lane bits 4,5) -> per-(row, wave) totals
    dssq  += __shfl_xor(dssq, 16);  dssq  += __shfl_xor(dssq, 32);
    qssq0 += __shfl_xor(qssq0, 16); qssq0 += __shfl_xor(qssq0, 32);
    qssq1 += __shfl_xor(qssq1, 16); qssq1 += __shfl_xor(qssq1, 32);

    #pragma unroll
    for (int j = 0; j < 4; j++) {
        red[wave][lane][j] = acc0[j];
        red[wave][lane][4 + j] = acc1[j];
    }
    red[wave][lane][8] = dssq;
    red[wave][lane][9] = qssq0;
    red[wave][lane][10] = qssq1;
    __syncthreads();

    if (tid < 16) {     // q-row inverse norms (rows tid and 16+tid)
        float q0 = 0.f, q1 = 0.f;
        #pragma unroll
        for (int w = 0; w < 4; w++) {
            q0 += red[w][tid][9];
            q1 += red[w][tid][10];
        }
        qinv[tid]      = 1.f / fmaxf(sqrtf(q0), 1e-13f);
        qinv[16 + tid] = 1.f / fmaxf(sqrtf(q1), 1e-13f);
    }
    __syncthreads();

    if (wave == 0) {
        float a0f[4] = {0.f, 0.f, 0.f, 0.f};
        float a1f[4] = {0.f, 0.f, 0.f, 0.f};
        float sf = 0.f;
        #pragma unroll
        for (int w = 0; w < 4; w++) {
            #pragma unroll
            for (int j = 0; j < 4; j++) {
                a0f[j] += red[w][lane][j];
                a1f[j] += red[w][lane][4 + j];
            }
            sf += red[w][lane][8];
        }
        float dinv = 1.f / fmaxf(sqrtf(sf), 1e-13f);
        if (d < DD) {
            #pragma unroll
            for (int j = 0; j < 4; j++) {
                int q0 = 4 * g + j;     // C row = 4g+j, col = ln
                cosm[((size_t)b * QQ + q0) * DD + d] = a0f[j] * dinv * qinv[q0];
                int q1i = 16 + q0;
                if (q1i < QQ)
                    cosm[((size_t)b * QQ + q1i) * DD + d] = a1f[j] * dinv * qinv[q1i];
            }
        }
    }
}

// ---------------------------------------------------------------------------
// Kernel 2: RBF (f32 __expf) -> window sums -> saturation -> pscore.
// Block per (b,q,chunk of 256 windows) = 720 blocks. No sync primitives.
// ---------------------------------------------------------------------------
__global__ __launch_bounds__(256) void skl_windows(
    const float* __restrict__ cosm,    // [8][30][1500]
    const float* __restrict__ dmask,   // [8][1500]
    const float* __restrict__ qmask,   // [8][30]
    const float* __restrict__ qidfs,   // [240]
    const float* __restrict__ mu,      // [11]
    const float* __restrict__ sigma,   // [11]
    const float* __restrict__ w1, const float* __restrict__ b1,
    const float* __restrict__ w2, const float* __restrict__ b2,
    const float* __restrict__ w3, const float* __restrict__ b3,
    const float* __restrict__ dw,      // [11]
    float* __restrict__ pscore)        // [240][736]
{
    __shared__ float vf[KK][DCH];      // 23.9 KB
    __shared__ float fl[DCH];          // 2.2 KB

    int bid = blockIdx.x;     // 0..719
    int c  = bid % 3;
    int bq = bid / 3;         // 0..239
    int b  = bq / QQ;
    int tid = threadIdx.x;

    int dbase = 512 * c;
    int dcount = min(540, DD - dbase);
    int w = c * 256 + tid;
    bool active = (w < WW);

    float muL[KK], i2s[KK], dwL[KK];
    #pragma unroll
    for (int k = 0; k < KK; k++) {
        muL[k] = mu[k];
        float s = sigma[k];
        i2s[k] = 1.f / (2.f * s * s);
        dwL[k] = dw[k];
    }
    const float* dm = dmask + (size_t)b * DD + dbase;
    const float* crow = cosm + (size_t)bq * DD + dbase;

    // phase 1: 11 RBF values per d
    for (int i = tid; i < dcount; i += 256) {
        float cc = crow[i];
        float m = dm[i];
        float ssum = 0.f;
        #pragma unroll
        for (int k = 0; k < KK; k++) {
            float diff = cc - muL[k];
            float val = __expf(-diff * diff * i2s[k]) * m;
            ssum += val;
            vf[k][i] = val;
        }
        fl[i] = (ssum != 0.f) ? 1.f : 0.f;
    }
    __syncthreads();

    // phase 2: per-window sums + saturation + dense_w
    if (active) {
        int dl = 2 * tid;
        float pk[KK];
        #pragma unroll
        for (int k = 0; k < KK; k++) pk[k] = 0.f;
        float lenf = 0.f;
        #pragma unroll
        for (int j2 = 0; j2 < WIN / 2; j2++) {
            float2 f2 = *(const float2*)&fl[dl + 2 * j2];
            lenf += f2.x + f2.y;
            #pragma unroll
            for (int k = 0; k < KK; k++) {
                float2 v2 = *(const float2*)&vf[k][dl + 2 * j2];
                pk[k] += v2.x + v2.y;
            }
        }
        float idf = fmaxf(qidfs[bq], 0.f);
        float sat1 = idf * w1[0] + lenf * w1[1] + b1[0];
        float sat2 = 1.f / (idf * w2[0] + lenf * w2[1] + b2[0]);
        float sat3 = idf * w3[0] + lenf * w3[1] + b3[0];
        float mult = qmask[bq] * (lenf > 0.f ? 1.f : 0.f);

        float acc = 0.f;
        #pragma unroll
        for (int k = 0; k < KK; k++) {
            float x = fmaxf(pk[k], 1e-10f);
            float p = exp2f(sat2 * __log2f(x));
            acc += (sat1 * p - sat3) * dwL[k];
        }
        pscore[(size_t)bq * WW + w] = acc * mult;
    }
}

// ---------------------------------------------------------------------------
// Kernel 3: per batch: sum over q (float4-vectorized), then single-wave
// top-3 argmax + pooling + gather.
// ---------------------------------------------------------------------------
__global__ __launch_bounds__(256) void skl_topk(
    const float* __restrict__ pscore,  // [240][736]
    const float* __restrict__ chunk,   // [15]
    float* __restrict__ out)           // [8]
{
    __shared__ float s0[WW];
    int b = blockIdx.x;
    int tid = threadIdx.x;

    if (tid < WW / 4) {                // 184 threads, one float4 of w each
        float4 s = make_float4(0.f, 0.f, 0.f, 0.f);
        for (int q = 0; q < QQ; q++) {
            float4 v = *(const float4*)&pscore[(size_t)(b * QQ + q) * WW + 4 * tid];
            s.x += v.x; s.y += v.y; s.z += v.z; s.w += v.w;
        }
        s0[4 * tid + 0] = (s.x == 0.f) ? -9900.f : s.x;
        s0[4 * tid + 1] = (s.y == 0.f) ? -9900.f : s.y;
        s0[4 * tid + 2] = (s.z == 0.f) ? -9900.f : s.z;
        s0[4 * tid + 3] = (s.w == 0.f) ? -9900.f : s.w;
    }
    __syncthreads();

    if (tid < 64) {
        int lane = tid;
        float m[12];
        #pragma unroll
        for (int r = 0; r < 12; r++) {
            int w = lane + 64 * r;
            m[r] = (w < WW) ? s0[w] : -3.3e38f;
        }

        int best[3];
        for (int c = 0; c < 3; c++) {
            float bv = -3.3e38f;
            int bi = 1 << 30;
            #pragma unroll
            for (int r = 0; r < 12; r++) {
                int w = lane + 64 * r;
                if (w < WW && m[r] > bv) { bv = m[r]; bi = w; }
            }
            #pragma unroll
            for (int off = 32; off >= 1; off >>= 1) {
                float ov = __shfl_down(bv, off);
                int oi = __shfl_down(bi, off);
                if (ov > bv || (ov == bv && oi < bi)) { bv = ov; bi = oi; }
            }
            bi = __shfl(bi, 0);
            best[c] = bi;
            float pen = -10001.f - (float)c;
            #pragma unroll
            for (int r = 0; r < 12; r++) {
                int w = lane + 64 * r;
                int dd = w - bi; if (dd < 0) dd = -dd;
                if (w < WW && dd < 15) m[r] = pen;
            }
        }

        float contrib = 0.f;
        if (lane < 15) {
            int c = lane % 3;
            int g = lane / 3;
            const int offs[5] = {0, -1, 1, -2, 2};
            int nb = best[c] + offs[g];
            nb = min(max(nb, 0), WW - 1);
            float v = s0[nb];
            if (v <= -9900.f) v = 0.f;
            contrib = v * chunk[lane];
        }
        #pragma unroll
        for (int off = 32; off >= 1; off >>= 1) contrib += __shfl_down(contrib, off);
        if (lane == 0) out[b] = contrib;
    }
}

// ---------------------------------------------------------------------------
extern "C" void kernel_launch(void* const* d_in, const int* in_sizes, int n_in,
                              void* d_out, int out_size, void* d_ws, size_t ws_size,
                              hipStream_t stream) {
    const float* qe    = (const float*)d_in[0];   // (8,30,768)
    const float* de    = (const float*)d_in[1];   // (8,1500,768)
    const float* qmask = (const float*)d_in[2];   // (8,30)
    const float* dmask = (const float*)d_in[3];   // (8,1500)
    const float* qidfs = (const float*)d_in[4];   // (8,30,1)
    // d_in[5] = document_idfs (unused)
    const float* mu    = (const float*)d_in[6];   // (11,)
    const float* sigma = (const float*)d_in[7];   // (11,)
    const float* w1    = (const float*)d_in[8];
    const float* b1    = (const float*)d_in[9];
    const float* w2    = (const float*)d_in[10];
    const float* b2    = (const float*)d_in[11];
    const float* w3    = (const float*)d_in[12];
    const float* b3    = (const float*)d_in[13];
    const float* dw    = (const float*)d_in[14];  // (1,11)
    const float* chunk = (const float*)d_in[15];  // (1,15)
    float* out = (float*)d_out;

    float* ws = (float*)d_ws;
    float* cosm   = ws;                      // 240*1500 = 360,000 f32
    float* pscore = ws + 360000;             // 240*736  = 176,640 f32  (~2.1MB)

    skl_gemm<<<dim3(NT, BB), 256, 0, stream>>>(qe, de, cosm);
    skl_windows<<<BB * QQ * 3, 256, 0, stream>>>(cosm, dmask, qmask, qidfs,
                                                 mu, sigma, w1, b1, w2, b2, w3, b3,
                                                 dw, pscore);
    skl_topk<<<BB, 256, 0, stream>>>(pscore, chunk, out);
}